// Round 1
// baseline (968.774 us; speedup 1.0000x reference)
//
#include <hip/hip_runtime.h>

#define B 8
#define CIN 320
#define C 256
#define P 16384
#define NCLS 21
#define NBN (B*P)          // 131072 samples per channel for BN
#define PT 64              // pixels per K1 block
#define CK 32              // c-chunk in K1
#define BLKS_PER_B 32
#define PIX_PER_BLK (P/BLKS_PER_B)   // 512
#define TT 16              // t-tile pixels in K4b

typedef unsigned short u16;

__device__ __forceinline__ float bf2f(u16 v){
    unsigned int u = ((unsigned int)v) << 16;
    float f; __builtin_memcpy(&f, &u, 4); return f;
}
__device__ __forceinline__ u16 f2bf(float f){
    unsigned int u; __builtin_memcpy(&u, &f, 4);
    unsigned int lsb = (u >> 16) & 1u;
    u += 0x7fffu + lsb;
    return (u16)(u >> 16);
}

// ---------- K0: transpose W (256x320) -> Wt (320x256) ----------
__global__ void k0_transpose(const float* __restrict__ W, float* __restrict__ Wt){
    int idx = blockIdx.x * 256 + threadIdx.x;
    if (idx < CIN * C){
        int c = idx / C, o = idx % C;
        Wt[c * C + o] = W[o * CIN + c];
    }
}

// ---------- K1: GEMM x[b,p,o] = sum_c s[b,c,p] * W[o,c]; write bf16 x; BN partial sums ----------
__global__ __launch_bounds__(256) void k1_gemm(const float* __restrict__ S,
                                               const float* __restrict__ Wt,
                                               u16* __restrict__ X,
                                               float* __restrict__ bnsum,
                                               float* __restrict__ bnsumsq){
    __shared__ float ss[CK][PT];
    __shared__ float wl[CK][C];
    const int t  = threadIdx.x;
    const int bid = blockIdx.x;
    const int b  = bid >> 8;              // 256 tiles per batch
    const int p0 = (bid & 255) * PT;
    const float* Sb = S + (size_t)b * CIN * P;

    float acc[PT];
    #pragma unroll
    for (int j = 0; j < PT; j++) acc[j] = 0.f;

    for (int c0 = 0; c0 < CIN; c0 += CK){
        #pragma unroll
        for (int l = 0; l < (CK*PT)/256; l++){
            int f = l * 256 + t;
            int i = f / PT, j = f % PT;
            ss[i][j] = Sb[(size_t)(c0 + i) * P + p0 + j];
        }
        #pragma unroll
        for (int l = 0; l < CK; l++){
            wl[l][t] = Wt[(c0 + l) * C + t];
        }
        __syncthreads();
        #pragma unroll
        for (int i = 0; i < CK; i++){
            float w = wl[i][t];
            const float4* s4 = reinterpret_cast<const float4*>(&ss[i][0]);
            #pragma unroll
            for (int j4 = 0; j4 < PT/4; j4++){
                float4 v = s4[j4];
                acc[j4*4+0] = fmaf(v.x, w, acc[j4*4+0]);
                acc[j4*4+1] = fmaf(v.y, w, acc[j4*4+1]);
                acc[j4*4+2] = fmaf(v.z, w, acc[j4*4+2]);
                acc[j4*4+3] = fmaf(v.w, w, acc[j4*4+3]);
            }
        }
        __syncthreads();
    }
    float s1 = 0.f, s2 = 0.f;
    u16* Xp = X + ((size_t)b * P + p0) * C + t;
    #pragma unroll
    for (int j = 0; j < PT; j++){
        float v = acc[j];
        s1 += v; s2 += v * v;
        Xp[(size_t)j * C] = f2bf(v);
    }
    atomicAdd(&bnsum[t],   s1);
    atomicAdd(&bnsumsq[t], s2);
}

// ---------- K2: finalize BN affine: a = gamma/sqrt(v+eps), b2 = beta - m*a ----------
__global__ void k2_bn(const float* __restrict__ bnsum, const float* __restrict__ bnsumsq,
                      const float* __restrict__ gamma, const float* __restrict__ beta,
                      float* __restrict__ A, float* __restrict__ B2){
    int o = threadIdx.x;
    float m = bnsum[o] / (float)NBN;
    float v = bnsumsq[o] / (float)NBN - m * m;
    float a = gamma[o] / sqrtf(v + 1e-5f);
    A[o]  = a;
    B2[o] = beta[o] - m * a;
}

// ---------- K3: per-batch class histogram ----------
__global__ void k3_counts(const int* __restrict__ gt, float* __restrict__ counts){
    __shared__ float h[NCLS];
    int b = blockIdx.x, t = threadIdx.x;
    if (t < NCLS) h[t] = 0.f;
    __syncthreads();
    for (int i = t; i < P; i += 256) atomicAdd(&h[gt[b * P + i]], 1.0f);
    __syncthreads();
    if (t < NCLS) counts[b * NCLS + t] = h[t];
}

// ---------- K4a: BN+ReLU+l2norm of x -> s_bar (in-place bf16); class stats for s ----------
__global__ __launch_bounds__(256) void k4a(u16* __restrict__ X, const int* __restrict__ gt,
                                           const float* __restrict__ A, const float* __restrict__ B2,
                                           float* __restrict__ gsum_s, float* __restrict__ gsumsq_s){
    __shared__ float lsum[NCLS * C];
    __shared__ float lsq [NCLS * C];
    __shared__ float red[4][4];
    const int t = threadIdx.x;
    const int b  = blockIdx.x / BLKS_PER_B;
    const int pb = (blockIdx.x % BLKS_PER_B) * PIX_PER_BLK;
    for (int i = t; i < NCLS * C; i += 256){ lsum[i] = 0.f; lsq[i] = 0.f; }
    const float a = A[t], b2 = B2[t];
    const int wid = t >> 6, lane = t & 63;
    u16* Xb = X + (size_t)b * P * C;
    const int* gtb = gt + b * P;
    __syncthreads();

    for (int p4 = 0; p4 < PIX_PER_BLK; p4 += 4){
        const int p = pb + p4;
        float sv[4], qq[4];
        #pragma unroll
        for (int q = 0; q < 4; q++){
            float x = bf2f(Xb[(size_t)(p + q) * C + t]);
            float val = fmaf(a, x, b2);
            float s = val > 0.f ? val : 0.f;
            sv[q] = s; qq[q] = s * s;
        }
        #pragma unroll
        for (int q = 0; q < 4; q++){
            float v = qq[q];
            for (int off = 32; off; off >>= 1) v += __shfl_xor(v, off, 64);
            if (lane == 0) red[q][wid] = v;
        }
        __syncthreads();
        #pragma unroll
        for (int q = 0; q < 4; q++){
            float n2 = red[q][0] + red[q][1] + red[q][2] + red[q][3];
            float rn = 1.0f / fmaxf(sqrtf(n2), 1e-12f);
            float sb = sv[q] * rn;
            int k = gtb[p + q];
            lsum[k * C + t] += sb;
            lsq [k * C + t] += sb * sb;
            Xb[(size_t)(p + q) * C + t] = f2bf(sb);
        }
        __syncthreads();
    }
    float* gs = gsum_s   + (size_t)b * NCLS * C;
    float* gq = gsumsq_s + (size_t)b * NCLS * C;
    for (int i = t; i < NCLS * C; i += 256){
        atomicAdd(&gs[i], lsum[i]);
        atomicAdd(&gq[i], lsq[i]);
    }
}

// ---------- K4b: l2norm of t -> t_bar; mse vs s_bar; class stats for t ----------
__global__ __launch_bounds__(256) void k4b(const float* __restrict__ Tf, const u16* __restrict__ Sbar,
                                           const int* __restrict__ gt,
                                           float* __restrict__ gsum_t, float* __restrict__ gsumsq_t,
                                           float* __restrict__ mse){
    __shared__ float lsum[NCLS * C];
    __shared__ float lsq [NCLS * C];
    __shared__ float ts[TT][C + 1];
    __shared__ float red[4][4];
    const int t = threadIdx.x;
    const int b  = blockIdx.x / BLKS_PER_B;
    const int pb = (blockIdx.x % BLKS_PER_B) * PIX_PER_BLK;
    for (int i = t; i < NCLS * C; i += 256){ lsum[i] = 0.f; lsq[i] = 0.f; }
    const int wid = t >> 6, lane = t & 63;
    float msea = 0.f;
    const float* Tb = Tf + (size_t)b * C * P;
    const int* gtb = gt + b * P;
    const u16* Sb = Sbar + (size_t)b * P * C;
    __syncthreads();

    for (int tile = 0; tile < PIX_PER_BLK / TT; tile++){
        const int p0 = pb + tile * TT;
        #pragma unroll
        for (int l = 0; l < TT; l++){
            int f = l * 256 + t;
            int c = f / TT, j = f % TT;
            ts[j][c] = Tb[(size_t)c * P + p0 + j];
        }
        __syncthreads();
        for (int j4 = 0; j4 < TT; j4 += 4){
            float tv[4];
            #pragma unroll
            for (int q = 0; q < 4; q++){
                float v0 = ts[j4 + q][t];
                tv[q] = v0;
                float v = v0 * v0;
                for (int off = 32; off; off >>= 1) v += __shfl_xor(v, off, 64);
                if (lane == 0) red[q][wid] = v;
            }
            __syncthreads();
            #pragma unroll
            for (int q = 0; q < 4; q++){
                float n2 = red[q][0] + red[q][1] + red[q][2] + red[q][3];
                float rn = 1.0f / fmaxf(sqrtf(n2), 1e-12f);
                float tb = tv[q] * rn;
                int p = p0 + j4 + q;
                float sb = bf2f(Sb[(size_t)p * C + t]);
                float d = sb - tb;
                msea += d * d;
                int k = gtb[p];
                lsum[k * C + t] += tb;
                lsq [k * C + t] += tb * tb;
            }
            __syncthreads();
        }
    }
    float* gs = gsum_t   + (size_t)b * NCLS * C;
    float* gq = gsumsq_t + (size_t)b * NCLS * C;
    for (int i = t; i < NCLS * C; i += 256){
        atomicAdd(&gs[i], lsum[i]);
        atomicAdd(&gq[i], lsq[i]);
    }
    float v = msea;
    for (int off = 32; off; off >>= 1) v += __shfl_xor(v, off, 64);
    __syncthreads();
    if (lane == 0) red[0][wid] = v;
    __syncthreads();
    if (t == 0) atomicAdd(mse, red[0][0] + red[0][1] + red[0][2] + red[0][3]);
}

// ---------- K5: final scalar loss ----------
__global__ void k5_final(const float* __restrict__ counts,
                         const float* __restrict__ gsum_s, const float* __restrict__ gsumsq_s,
                         const float* __restrict__ gsum_t, const float* __restrict__ gsumsq_t,
                         const float* __restrict__ mse, float* __restrict__ out){
    __shared__ float red[2][4];
    __shared__ float acc[2];
    const int t = threadIdx.x, wid = t >> 6, lane = t & 63;
    if (t == 0){ acc[0] = 0.f; acc[1] = 0.f; }
    __syncthreads();
    for (int bk = 0; bk < B * NCLS; bk++){
        int k = bk % NCLS;
        float cnt = counts[bk];
        int idx = bk * C + t;
        float cs = fmaxf(cnt, 1.f);
        float dn = fmaxf(cnt - 1.f, 1.f);
        float mu_s  = gsum_s[idx] / cs;
        float var_s = (gsumsq_s[idx] - cnt * mu_s * mu_s) / dn + 1e-6f;
        float mu_t  = gsum_t[idx] / cs;
        float var_t = (gsumsq_t[idx] - cnt * mu_t * mu_t) / dn + 1e-6f;
        float dmu = mu_s - mu_t, dv = var_s - var_t;
        float a1 = dmu * dmu, a2 = dv * dv;
        for (int off = 32; off; off >>= 1){ a1 += __shfl_xor(a1, off, 64); a2 += __shfl_xor(a2, off, 64); }
        if (lane == 0){ red[0][wid] = a1; red[1][wid] = a2; }
        __syncthreads();
        if (t == 0){
            float lm = (red[0][0] + red[0][1] + red[0][2] + red[0][3]) / (float)C;
            float lv = (red[1][0] + red[1][1] + red[1][2] + red[1][3]) / (float)C;
            if (cnt > 1.f && k != 0){
                acc[0] += 0.5f * lm + 0.5f * lv;
                acc[1] += 1.f;
            }
        }
        __syncthreads();
    }
    if (t == 0){
        out[0] = acc[0] / (acc[1] + 1e-7f) + 0.5f * (mse[0] / (float)((size_t)B * C * P));
    }
}

extern "C" void kernel_launch(void* const* d_in, const int* in_sizes, int n_in,
                              void* d_out, int out_size, void* d_ws, size_t ws_size,
                              hipStream_t stream){
    (void)in_sizes; (void)n_in; (void)out_size; (void)ws_size;
    const float* s_feat = (const float*)d_in[0];
    const float* t_feat = (const float*)d_in[1];
    const int*   gt     = (const int*)d_in[2];
    const float* Wp     = (const float*)d_in[3];
    const float* gamma  = (const float*)d_in[4];
    const float* beta   = (const float*)d_in[5];
    float* out = (float*)d_out;
    char* ws = (char*)d_ws;

    // workspace layout
    const size_t X_OFF   = 0;                                     // bf16 x / s_bar: 67,108,864 B
    const size_t WT_OFF  = (size_t)B * P * C * 2;                 // 67,108,864
    const size_t Z0      = WT_OFF + (size_t)CIN * C * 4;          // zero region start
    const size_t STATSZ  = (size_t)B * NCLS * C * 4;              // 172,032 B each
    u16*   X        = (u16*)(ws + X_OFF);
    float* Wt       = (float*)(ws + WT_OFF);
    float* bnsum    = (float*)(ws + Z0);
    float* bnsumsq  = (float*)(ws + Z0 + 1024);
    float* gsum_s   = (float*)(ws + Z0 + 2048);
    float* gsumsq_s = (float*)(ws + Z0 + 2048 + STATSZ);
    float* gsum_t   = (float*)(ws + Z0 + 2048 + 2 * STATSZ);
    float* gsumsq_t = (float*)(ws + Z0 + 2048 + 3 * STATSZ);
    float* mse      = (float*)(ws + Z0 + 2048 + 4 * STATSZ);
    float* Abuf     = (float*)(ws + Z0 + 2048 + 4 * STATSZ + 1024);
    float* B2buf    = (float*)(ws + Z0 + 2048 + 4 * STATSZ + 2048);
    float* counts   = (float*)(ws + Z0 + 2048 + 4 * STATSZ + 3072);

    const size_t zeroBytes = 2048 + 4 * STATSZ + 1024;  // bn sums + stats + mse (+pad)
    hipMemsetAsync(ws + Z0, 0, zeroBytes, stream);

    k0_transpose<<<(CIN * C + 255) / 256, 256, 0, stream>>>(Wp, Wt);
    k1_gemm<<<B * (P / PT), 256, 0, stream>>>(s_feat, Wt, X, bnsum, bnsumsq);
    k2_bn<<<1, C, 0, stream>>>(bnsum, bnsumsq, gamma, beta, Abuf, B2buf);
    k3_counts<<<B, 256, 0, stream>>>(gt, counts);
    k4a<<<B * BLKS_PER_B, 256, 0, stream>>>(X, gt, Abuf, B2buf, gsum_s, gsumsq_s);
    k4b<<<B * BLKS_PER_B, 256, 0, stream>>>(t_feat, X, gt, gsum_t, gsumsq_t, mse);
    k5_final<<<1, 256, 0, stream>>>(counts, gsum_s, gsumsq_s, gsum_t, gsumsq_t, mse, out);
}